// Round 1
// 169.888 us; speedup vs baseline: 1.0983x; 1.0983x over previous
//
#include <hip/hip_runtime.h>
#include <cstdint>
#include <cstddef>

typedef unsigned short u16;
typedef unsigned int u32;
typedef unsigned char u8;

using bfx8 = __attribute__((ext_vector_type(8))) __bf16;
using floatx16 = __attribute__((ext_vector_type(16))) float;

// B=8, S=1024, D=768, H=12, DH=64
static constexpr int kS = 1024;
static constexpr int kD = 768;
static constexpr int kH = 12;
static constexpr int kDH = 64;
#define SCALE 0.036084391824351614f  // 1/sqrt(768)

__device__ __forceinline__ u16 f2bf(float f) {
    u32 u = __float_as_uint(f);
    return (u16)((u + 0x7fffu + ((u >> 16) & 1u)) >> 16);
}

// async global->LDS, 16B per lane. LDS dst = uniform base + lane*16.
__device__ __forceinline__ void gld16(const void* g, void* l) {
    __builtin_amdgcn_global_load_lds(
        (__attribute__((address_space(1))) const u32*)g,
        (__attribute__((address_space(3))) u32*)l, 16, 0, 0);
}

// ---------------- kernel 1: x fp32 -> bf16 ----------------
__global__ __launch_bounds__(256) void cvt_x(const float* __restrict__ x, u16* __restrict__ xb) {
    int i = (blockIdx.x * 256 + threadIdx.x) * 4;
    float4 v = *(const float4*)(x + i);
    u32 lo = (u32)f2bf(v.x) | ((u32)f2bf(v.y) << 16);
    u32 hi = (u32)f2bf(v.z) | ((u32)f2bf(v.w) << 16);
    *(uint2*)(xb + i) = make_uint2(lo, hi);
}

// ---------------- kernel 2: W (k,n) fp32 -> Wt (n,k) bf16, concat 3 -> [2304][768] ----------------
__global__ __launch_bounds__(256) void cvt_w(const float* __restrict__ w0, const float* __restrict__ w1,
                                             const float* __restrict__ w2, u16* __restrict__ wt) {
    __shared__ float t[32][33];
    const float* W = blockIdx.z == 0 ? w0 : (blockIdx.z == 1 ? w1 : w2);
    u16* dst = wt + (size_t)blockIdx.z * kD * kD;
    int k0 = blockIdx.x * 32, n0 = blockIdx.y * 32;
    int tx = threadIdx.x, ty = threadIdx.y;  // 32 x 8
#pragma unroll
    for (int j = 0; j < 4; j++)
        t[ty + j * 8][tx] = W[(size_t)(k0 + ty + j * 8) * kD + n0 + tx];
    __syncthreads();
#pragma unroll
    for (int j = 0; j < 4; j++)
        dst[(size_t)(n0 + ty + j * 8) * kD + k0 + tx] = f2bf(t[tx][ty + j * 8]);
}

// ---------------- kernel 3: fused QKV projection GEMM (32x32x16 MFMA) ----------------
// C[8192 x 2304] = Xb[8192 x 768] @ [Wq|Wk|Wv]^T-rows + bias.
// T3-minimum 2-phase: double-buffered LDS, stage(next) issued BEFORE compute(cur),
// single vmcnt(0)-drain+barrier per K-step (the __syncthreads at loop end).
// Q gets *SCALE folded in. V stored transposed per-head (b,h,dh,s) with sigma-permuted
// s index (swap bits 2<->3) so attn's PV A-fragments come straight from registers.
__global__ __launch_bounds__(256) void proj(const u16* __restrict__ xb, const u16* __restrict__ wt,
                                            const float* __restrict__ bq, const float* __restrict__ bk,
                                            const float* __restrict__ bvp,
                                            u16* __restrict__ qb, u16* __restrict__ kb, u16* __restrict__ vt) {
    __shared__ u16 As0[128 * 64];
    __shared__ u16 Bs0[128 * 64];
    __shared__ u16 As1[128 * 64];
    __shared__ u16 Bs1[128 * 64];
    int m0 = blockIdx.x * 128;
    int n0g = blockIdx.y * 128;
    int t = threadIdx.x;
    int w = t >> 6, lane = t & 63;
    int l31 = lane & 31, hi = lane >> 5;
    int wm = (w & 1) * 64, wn = (w >> 1) * 64;
    int rloc8 = lane >> 3, p8 = lane & 7;
    int chw = p8 ^ rloc8;  // global-side logical chunk for this lane's phys slot
    const u16* Brow = wt + (size_t)n0g * kD;
    int swz = l31 & 7;
    floatx16 acc[2][2] = {};

    auto STAGE = [&](u16* Ad, u16* Bd, int ks) {
#pragma unroll
        for (int i = 0; i < 4; i++) {
            int j = w * 4 + i;
            int r = 8 * j + rloc8;
            gld16(xb + (size_t)(m0 + r) * kD + ks + chw * 8, Ad + j * 512);
            gld16(Brow + (size_t)r * kD + ks + chw * 8, Bd + j * 512);
        }
    };
    auto COMP = [&](const u16* Ad, const u16* Bd) {
#pragma unroll
        for (int s = 0; s < 4; s++) {
            int tc = ((s * 2 + hi) ^ swz) * 8;
            bfx8 a[2], bf[2];
#pragma unroll
            for (int i = 0; i < 2; i++) {
                a[i] = *(const bfx8*)&Ad[(wm + i * 32 + l31) * 64 + tc];
                bf[i] = *(const bfx8*)&Bd[(wn + i * 32 + l31) * 64 + tc];
            }
#pragma unroll
            for (int i = 0; i < 2; i++)
#pragma unroll
                for (int j2 = 0; j2 < 2; j2++)
                    acc[i][j2] = __builtin_amdgcn_mfma_f32_32x32x16_bf16(a[i], bf[j2], acc[i][j2], 0, 0, 0);
        }
    };

    // prologue: stage ks=0 into buffer 0
    STAGE(As0, Bs0, 0);
    __syncthreads();
    // 5 unrolled-by-2 pairs: stages 64..640, computes 0..576
    for (int kk = 0; kk < 5; kk++) {
        STAGE(As1, Bs1, 64 + 128 * kk);
        COMP(As0, Bs0);
        __syncthreads();
        STAGE(As0, Bs0, 128 + 128 * kk);
        COMP(As1, Bs1);
        __syncthreads();
    }
    STAGE(As1, Bs1, 704);
    COMP(As0, Bs0);
    __syncthreads();
    COMP(As1, Bs1);

    // epilogue: C/D layout col=lane&31, row=(reg&3)+8*(reg>>2)+4*(lane>>5)
    int zz = blockIdx.y / 6;                  // 0=Q 1=K 2=V
    int nl0 = (blockIdx.y - zz * 6) * 128;
    const float* bias = zz == 0 ? bq : (zz == 1 ? bk : bvp);
    float mul = zz == 0 ? SCALE : 1.0f;
#pragma unroll
    for (int j = 0; j < 2; j++) {
        int nl = nl0 + wn + j * 32 + l31;
        float bb = bias[nl];
#pragma unroll
        for (int i = 0; i < 2; i++) {
            int mbase = m0 + wm + i * 32 + 4 * hi;
            if (zz < 2) {
                u16* dst = zz == 0 ? qb : kb;
#pragma unroll
                for (int reg = 0; reg < 16; reg++) {
                    int m = mbase + (reg & 3) + 8 * (reg >> 2);
                    dst[(size_t)m * kD + nl] = f2bf((acc[i][j][reg] + bb) * mul);
                }
            } else {
                int hh = nl >> 6, dh = nl & 63;
#pragma unroll
                for (int g = 0; g < 4; g++) {
                    // sigma-permuted store: original s had bit2=hi, bit3=g&1; swap them.
                    int m = (m0 + wm + i * 32) + 4 * (g & 1) + 8 * hi + 16 * (g >> 1);
                    int bi = m >> 10, s = m & 1023;
                    u32 lo = (u32)f2bf(acc[i][j][4 * g + 0] + bb) | ((u32)f2bf(acc[i][j][4 * g + 1] + bb) << 16);
                    u32 h2 = (u32)f2bf(acc[i][j][4 * g + 2] + bb) | ((u32)f2bf(acc[i][j][4 * g + 3] + bb) << 16);
                    *(uint2*)&vt[(((size_t)bi * kH + hh) * kDH + dh) * kS + s] = make_uint2(lo, h2);
                }
            }
        }
    }
}

// ---------------- kernel 4: flash attention, 32x32x16 MFMA, in-register P ----------------
// grid (S/128, B*H), 256 thr = 4 waves. Wave w owns q rows w*32..w*32+31 and computes the
// FULL 128-kpos S^T tile for them (S^T = K·Q^T: lane's sacc col = its q row).
// P never touches LDS: vt columns are sigma-permuted (s bits 2<->3 swapped at proj store),
// which makes PV instr s's A-fragment = bf16(sacc[s>>1][8*(s&1)..+7]) in natural register
// order (derivation: slot kappa=16s+8hi+4b+m needs kpos sigma(kappa)=16s+8b+4hi+m, which is
// reg 4*(2*(s&1)+b)+m of frag s>>1 — bit2=4hi matches what the lane holds).
// 2 barriers per K/V tile (was 4), no P LDS round-trip, no cross-lane ops.
__global__ __launch_bounds__(256, 3) void attn(const u16* __restrict__ qb, const u16* __restrict__ kb,
                                               const u16* __restrict__ vt, float* __restrict__ out) {
    __shared__ u16 Ks[128 * 64];   // K [kpos][64dh], chunk swz ^(r&7)
    __shared__ u16 Vs[64 * 128];   // V^T [dh][128 kappa], chunk swz ^(dh&15)
    __shared__ float Lw[128];
    int q0 = blockIdx.x * 128;
    int bh = blockIdx.y;
    int b = bh / kH, h = bh % kH;
    int t = threadIdx.x, w = t >> 6, lane = t & 63;
    int l31 = lane & 31, hi = lane >> 5;
    int swz = l31 & 7;

    // Q register fragments (B operand: col=q=w*32+l31, k=dh): 4 frags cover dh 0..63
    bfx8 qf[4];
    {
        const u16* qrow = qb + (size_t)(b * kS + q0 + w * 32 + l31) * kD + h * kDH + hi * 8;
#pragma unroll
        for (int f = 0; f < 4; f++) qf[f] = *(const bfx8*)(qrow + f * 16);
    }

    float rsum = 0.f;
    floatx16 oacc[2] = {};

    for (int kt = 0; kt < 8; kt++) {
        int kk0 = kt * 128;
        __syncthreads();  // prev tile's K/V reads done before overwrite
        // stage K: 16 KB; wave w does jj=4w..4w+3; lane: row 8jj+(l>>3), phys chunk l&7
#pragma unroll
        for (int i = 0; i < 4; i++) {
            int jj = 4 * w + i;
            int r = 8 * jj + (lane >> 3);
            int c = (lane & 7) ^ ((lane >> 3) & 7);
            gld16(kb + (size_t)(b * kS + kk0 + r) * kD + h * kDH + c * 8, &Ks[jj * 512]);
        }
        // stage V^T: 16 KB; lane: row 4jj+(l>>4), phys chunk l&15
#pragma unroll
        for (int i = 0; i < 4; i++) {
            int jj = 4 * w + i;
            int r = 4 * jj + (lane >> 4);
            int c = (lane & 15) ^ (r & 15);
            gld16(vt + (((size_t)b * kH + h) * kDH + r) * kS + kk0 + c * 8, &Vs[jj * 512]);
        }
        __syncthreads();  // drain gld16 + publish

        // S^T: frag fm rows = kpos 32fm+l31, cols q = w*32+l31
        floatx16 sacc[4] = {};
#pragma unroll
        for (int s2 = 0; s2 < 4; s2++) {
#pragma unroll
            for (int fm = 0; fm < 4; fm++) {
                bfx8 ak = *(const bfx8*)&Ks[(fm * 32 + l31) * 64 + ((s2 * 2 + hi) ^ swz) * 8];
                sacc[fm] = __builtin_amdgcn_mfma_f32_32x32x16_bf16(ak, qf[s2], sacc[fm], 0, 0, 0);
            }
        }

        // exp + pack to PV A-fragments, fully in-register
        bfx8 pa[4][2];
#pragma unroll
        for (int fm = 0; fm < 4; fm++) {
#pragma unroll
            for (int hh = 0; hh < 2; hh++) {
                bfx8 pv;
#pragma unroll
                for (int jj = 0; jj < 8; jj++) {
                    float e = __expf(sacc[fm][8 * hh + jj]);
                    rsum += e;
                    pv[jj] = (__bf16)e;
                }
                pa[fm][hh] = pv;
            }
        }

        // O += P·V over sigma-space kappa: A = pa[s>>1][s&1], B = Vs rows dh = db*32+l31
#pragma unroll
        for (int s = 0; s < 8; s++) {
#pragma unroll
            for (int db = 0; db < 2; db++) {
                bfx8 bv = *(const bfx8*)((const u8*)Vs + (db * 32 + l31) * 256 + (((s * 2 + hi) ^ (l31 & 15)) * 16));
                oacc[db] = __builtin_amdgcn_mfma_f32_32x32x16_bf16(pa[s >> 1][s & 1], bv, oacc[db], 0, 0, 0);
            }
        }
    }

    // lane holds sum over kpos with bit2==4*hi for q=l31; fold partner across lane^32
    rsum += __shfl_xor(rsum, 32, 64);
    if (lane < 32) Lw[w * 32 + lane] = rsum;
    __syncthreads();
    // O: col = dh = db*32+l31, row = q = w*32 + (reg&3)+8*(reg>>2)+4*hi
#pragma unroll
    for (int g = 0; g < 4; g++) {
#pragma unroll
        for (int r2 = 0; r2 < 4; r2++) {
            int qloc = w * 32 + 4 * hi + r2 + 8 * g;
            float linv = 1.0f / Lw[qloc];
#pragma unroll
            for (int db = 0; db < 2; db++) {
                out[(size_t)(b * kS + q0 + qloc) * kD + h * kDH + db * 32 + l31] = oacc[db][4 * g + r2] * linv;
            }
        }
    }
}

extern "C" void kernel_launch(void* const* d_in, const int* in_sizes, int n_in,
                              void* d_out, int out_size, void* d_ws, size_t ws_size,
                              hipStream_t stream) {
    const float* x  = (const float*)d_in[0];
    const float* Wq = (const float*)d_in[1];
    const float* bq = (const float*)d_in[2];
    const float* Wk = (const float*)d_in[3];
    const float* bk = (const float*)d_in[4];
    const float* Wv = (const float*)d_in[5];
    const float* bv = (const float*)d_in[6];
    float* out = (float*)d_out;

    u16* ws = (u16*)d_ws;
    u16* xb = ws;                   // 8192*768
    u16* wt = xb + 6291456;         // 3*768*768 concat [2304][768]
    u16* qb = wt + 1769472;         // scaled Q bf16
    u16* kb = qb + 6291456;
    u16* vt = kb + 6291456;         // V^T per head (b,h,dh,s), s sigma-permuted (bits 2<->3)

    cvt_x<<<dim3(6144), dim3(256), 0, stream>>>(x, xb);
    cvt_w<<<dim3(24, 24, 3), dim3(32, 8), 0, stream>>>(Wq, Wk, Wv, wt);
    proj<<<dim3(64, 18), dim3(256), 0, stream>>>(xb, wt, bq, bk, bv, qb, kb, vt);
    attn<<<dim3(8, 96), dim3(256), 0, stream>>>(qb, kb, vt, out);
}

// Round 2
// 165.810 us; speedup vs baseline: 1.1254x; 1.0246x over previous
//
#include <hip/hip_runtime.h>
#include <cstdint>
#include <cstddef>

typedef unsigned short u16;
typedef unsigned int u32;
typedef unsigned char u8;

using bfx8 = __attribute__((ext_vector_type(8))) __bf16;
using floatx16 = __attribute__((ext_vector_type(16))) float;

// B=8, S=1024, D=768, H=12, DH=64
static constexpr int kS = 1024;
static constexpr int kD = 768;
static constexpr int kH = 12;
static constexpr int kDH = 64;
#define SCALE 0.036084391824351614f  // 1/sqrt(768)

__device__ __forceinline__ u16 f2bf(float f) {
    u32 u = __float_as_uint(f);
    return (u16)((u + 0x7fffu + ((u >> 16) & 1u)) >> 16);
}

// async global->LDS, 16B per lane. LDS dst = uniform base + lane*16.
__device__ __forceinline__ void gld16(const void* g, void* l) {
    __builtin_amdgcn_global_load_lds(
        (__attribute__((address_space(1))) const u32*)g,
        (__attribute__((address_space(3))) u32*)l, 16, 0, 0);
}

// ---------------- kernel 1: fused converts ----------------
// blocks [0,6144): x fp32 -> bf16.  blocks [6144,7872): W (k,n) fp32 -> Wt (n,k) bf16 concat.
__global__ __launch_bounds__(256) void cvt(const float* __restrict__ x, u16* __restrict__ xb,
                                           const float* __restrict__ w0, const float* __restrict__ w1,
                                           const float* __restrict__ w2, u16* __restrict__ wt) {
    __shared__ float t[32][33];
    int bid = blockIdx.x;
    if (bid < 6144) {
        int i = (bid * 256 + threadIdx.x) * 4;
        float4 v = *(const float4*)(x + i);
        u32 lo = (u32)f2bf(v.x) | ((u32)f2bf(v.y) << 16);
        u32 hi = (u32)f2bf(v.z) | ((u32)f2bf(v.w) << 16);
        *(uint2*)(xb + i) = make_uint2(lo, hi);
    } else {
        int idx = bid - 6144;
        int z = idx / 576;
        int rem = idx - z * 576;
        int by = rem / 24, bx = rem - by * 24;
        const float* W = z == 0 ? w0 : (z == 1 ? w1 : w2);
        u16* dst = wt + (size_t)z * kD * kD;
        int k0 = bx * 32, n0 = by * 32;
        int tx = threadIdx.x & 31, ty = threadIdx.x >> 5;  // 32 x 8
#pragma unroll
        for (int j = 0; j < 4; j++)
            t[ty + j * 8][tx] = W[(size_t)(k0 + ty + j * 8) * kD + n0 + tx];
        __syncthreads();
#pragma unroll
        for (int j = 0; j < 4; j++)
            dst[(size_t)(n0 + ty + j * 8) * kD + k0 + tx] = f2bf(t[tx][ty + j * 8]);
    }
}

// ---------------- kernel 2: fused QKV projection GEMM (32x32x16 MFMA) ----------------
// C[8192 x 2304] = Xb[8192 x 768] @ [Wq|Wk|Wv]^T-rows + bias.
// T3-minimum 2-phase: double-buffered LDS, stage(next) issued BEFORE compute(cur).
// T1 chunked-bijective XCD swizzle, n-fastest within chunk: each XCD owns a contiguous
// m-range; all of wt (3.4 MB) stays resident in that XCD's 4 MB L2 and each A-panel is
// shared by 18 consecutive same-XCD blocks -> staging becomes L2-hit instead of L3.
// Q gets *SCALE folded in. V stored transposed per-head (b,h,dh,s), s sigma-permuted.
__global__ __launch_bounds__(256) void proj(const u16* __restrict__ xb, const u16* __restrict__ wt,
                                            const float* __restrict__ bq, const float* __restrict__ bk,
                                            const float* __restrict__ bvp,
                                            u16* __restrict__ qb, u16* __restrict__ kb, u16* __restrict__ vt) {
    __shared__ u16 As0[128 * 64];
    __shared__ u16 Bs0[128 * 64];
    __shared__ u16 As1[128 * 64];
    __shared__ u16 Bs1[128 * 64];
    // XCD swizzle: nwg=1152, 8 XCDs, q=144, r=0 -> wg = (orig%8)*144 + orig/8 (bijective).
    int orig = blockIdx.x;
    int wg = (orig & 7) * 144 + (orig >> 3);
    int mt = wg / 18, nt = wg - mt * 18;   // n-fastest within each XCD chunk
    int m0 = mt * 128;
    int n0g = nt * 128;
    int t = threadIdx.x;
    int w = t >> 6, lane = t & 63;
    int l31 = lane & 31, hi = lane >> 5;
    int wm = (w & 1) * 64, wn = (w >> 1) * 64;
    int rloc8 = lane >> 3, p8 = lane & 7;
    int chw = p8 ^ rloc8;  // global-side logical chunk for this lane's phys slot
    const u16* Brow = wt + (size_t)n0g * kD;
    int swz = l31 & 7;
    floatx16 acc[2][2] = {};

    auto STAGE = [&](u16* Ad, u16* Bd, int ks) {
#pragma unroll
        for (int i = 0; i < 4; i++) {
            int j = w * 4 + i;
            int r = 8 * j + rloc8;
            gld16(xb + (size_t)(m0 + r) * kD + ks + chw * 8, Ad + j * 512);
            gld16(Brow + (size_t)r * kD + ks + chw * 8, Bd + j * 512);
        }
    };
    auto COMP = [&](const u16* Ad, const u16* Bd) {
#pragma unroll
        for (int s = 0; s < 4; s++) {
            int tc = ((s * 2 + hi) ^ swz) * 8;
            bfx8 a[2], bf[2];
#pragma unroll
            for (int i = 0; i < 2; i++) {
                a[i] = *(const bfx8*)&Ad[(wm + i * 32 + l31) * 64 + tc];
                bf[i] = *(const bfx8*)&Bd[(wn + i * 32 + l31) * 64 + tc];
            }
#pragma unroll
            for (int i = 0; i < 2; i++)
#pragma unroll
                for (int j2 = 0; j2 < 2; j2++)
                    acc[i][j2] = __builtin_amdgcn_mfma_f32_32x32x16_bf16(a[i], bf[j2], acc[i][j2], 0, 0, 0);
        }
    };

    // prologue: stage ks=0 into buffer 0
    STAGE(As0, Bs0, 0);
    __syncthreads();
    // 5 unrolled-by-2 pairs: stages 64..640, computes 0..576
    for (int kk = 0; kk < 5; kk++) {
        STAGE(As1, Bs1, 64 + 128 * kk);
        COMP(As0, Bs0);
        __syncthreads();
        STAGE(As0, Bs0, 128 + 128 * kk);
        COMP(As1, Bs1);
        __syncthreads();
    }
    STAGE(As1, Bs1, 704);
    COMP(As0, Bs0);
    __syncthreads();
    COMP(As1, Bs1);

    // epilogue: C/D layout col=lane&31, row=(reg&3)+8*(reg>>2)+4*(lane>>5)
    int zz = nt / 6;                  // 0=Q 1=K 2=V
    int nl0 = (nt - zz * 6) * 128;
    const float* bias = zz == 0 ? bq : (zz == 1 ? bk : bvp);
    float mul = zz == 0 ? SCALE : 1.0f;
#pragma unroll
    for (int j = 0; j < 2; j++) {
        int nl = nl0 + wn + j * 32 + l31;
        float bb = bias[nl];
#pragma unroll
        for (int i = 0; i < 2; i++) {
            int mbase = m0 + wm + i * 32 + 4 * hi;
            if (zz < 2) {
                u16* dst = zz == 0 ? qb : kb;
#pragma unroll
                for (int reg = 0; reg < 16; reg++) {
                    int m = mbase + (reg & 3) + 8 * (reg >> 2);
                    dst[(size_t)m * kD + nl] = f2bf((acc[i][j][reg] + bb) * mul);
                }
            } else {
                int hh = nl >> 6, dh = nl & 63;
#pragma unroll
                for (int g = 0; g < 4; g++) {
                    // sigma-permuted store: original s had bit2=hi, bit3=g&1; swap them.
                    int m = (m0 + wm + i * 32) + 4 * (g & 1) + 8 * hi + 16 * (g >> 1);
                    int bi = m >> 10, s = m & 1023;
                    u32 lo = (u32)f2bf(acc[i][j][4 * g + 0] + bb) | ((u32)f2bf(acc[i][j][4 * g + 1] + bb) << 16);
                    u32 h2 = (u32)f2bf(acc[i][j][4 * g + 2] + bb) | ((u32)f2bf(acc[i][j][4 * g + 3] + bb) << 16);
                    *(uint2*)&vt[(((size_t)bi * kH + hh) * kDH + dh) * kS + s] = make_uint2(lo, h2);
                }
            }
        }
    }
}

// ---------------- kernel 3: flash attention, 32x32x16 MFMA, in-register P ----------------
// grid 768 blocks (swizzled), 256 thr = 4 waves. Wave w owns q rows w*32..+31, computes the
// FULL 128-kpos S^T tile for them (S^T = K·Q^T: lane's sacc col = its q row).
// P never touches LDS (sigma-permuted vt makes PV A-frags register-natural).
// T1 chunked XCD swizzle: 8 consecutive same-XCD blocks share one (b,h) K/V head (256 KB,
// L2-resident) -> K/V staging becomes L2-hit.
__global__ __launch_bounds__(256, 3) void attn(const u16* __restrict__ qb, const u16* __restrict__ kb,
                                               const u16* __restrict__ vt, float* __restrict__ out) {
    __shared__ u16 Ks[128 * 64];   // K [kpos][64dh], chunk swz ^(r&7)
    __shared__ u16 Vs[64 * 128];   // V^T [dh][128 kappa], chunk swz ^(dh&15)
    __shared__ float Lw[128];
    // XCD swizzle: nwg=768, q=96, r=0 -> wg = (orig%8)*96 + orig/8 (bijective).
    int orig = blockIdx.x;
    int wg = (orig & 7) * 96 + (orig >> 3);
    int bh = wg >> 3;          // head index; 8 consecutive same-XCD blocks share it
    int q0 = (wg & 7) * 128;
    int b = bh / kH, h = bh % kH;
    int t = threadIdx.x, w = t >> 6, lane = t & 63;
    int l31 = lane & 31, hi = lane >> 5;
    int swz = l31 & 7;

    // Q register fragments (B operand: col=q=w*32+l31, k=dh): 4 frags cover dh 0..63
    bfx8 qf[4];
    {
        const u16* qrow = qb + (size_t)(b * kS + q0 + w * 32 + l31) * kD + h * kDH + hi * 8;
#pragma unroll
        for (int f = 0; f < 4; f++) qf[f] = *(const bfx8*)(qrow + f * 16);
    }

    float rsum = 0.f;
    floatx16 oacc[2] = {};

    for (int kt = 0; kt < 8; kt++) {
        int kk0 = kt * 128;
        __syncthreads();  // prev tile's K/V reads done before overwrite
        // stage K: 16 KB; wave w does jj=4w..4w+3; lane: row 8jj+(l>>3), phys chunk l&7
#pragma unroll
        for (int i = 0; i < 4; i++) {
            int jj = 4 * w + i;
            int r = 8 * jj + (lane >> 3);
            int c = (lane & 7) ^ ((lane >> 3) & 7);
            gld16(kb + (size_t)(b * kS + kk0 + r) * kD + h * kDH + c * 8, &Ks[jj * 512]);
        }
        // stage V^T: 16 KB; lane: row 4jj+(l>>4), phys chunk l&15
#pragma unroll
        for (int i = 0; i < 4; i++) {
            int jj = 4 * w + i;
            int r = 4 * jj + (lane >> 4);
            int c = (lane & 15) ^ (r & 15);
            gld16(vt + (((size_t)b * kH + h) * kDH + r) * kS + kk0 + c * 8, &Vs[jj * 512]);
        }
        __syncthreads();  // drain gld16 + publish

        // S^T: frag fm rows = kpos 32fm+l31, cols q = w*32+l31
        floatx16 sacc[4] = {};
#pragma unroll
        for (int s2 = 0; s2 < 4; s2++) {
#pragma unroll
            for (int fm = 0; fm < 4; fm++) {
                bfx8 ak = *(const bfx8*)&Ks[(fm * 32 + l31) * 64 + ((s2 * 2 + hi) ^ swz) * 8];
                sacc[fm] = __builtin_amdgcn_mfma_f32_32x32x16_bf16(ak, qf[s2], sacc[fm], 0, 0, 0);
            }
        }

        // exp + pack to PV A-fragments, fully in-register
        bfx8 pa[4][2];
#pragma unroll
        for (int fm = 0; fm < 4; fm++) {
#pragma unroll
            for (int hh = 0; hh < 2; hh++) {
                bfx8 pv;
#pragma unroll
                for (int jj = 0; jj < 8; jj++) {
                    float e = __expf(sacc[fm][8 * hh + jj]);
                    rsum += e;
                    pv[jj] = (__bf16)e;
                }
                pa[fm][hh] = pv;
            }
        }

        // O += P·V over sigma-space kappa: A = pa[s>>1][s&1], B = Vs rows dh = db*32+l31
#pragma unroll
        for (int s = 0; s < 8; s++) {
#pragma unroll
            for (int db = 0; db < 2; db++) {
                bfx8 bv = *(const bfx8*)((const u8*)Vs + (db * 32 + l31) * 256 + (((s * 2 + hi) ^ (l31 & 15)) * 16));
                oacc[db] = __builtin_amdgcn_mfma_f32_32x32x16_bf16(pa[s >> 1][s & 1], bv, oacc[db], 0, 0, 0);
            }
        }
    }

    // lane holds sum over kpos with bit2==4*hi for q=l31; fold partner across lane^32
    rsum += __shfl_xor(rsum, 32, 64);
    if (lane < 32) Lw[w * 32 + lane] = rsum;
    __syncthreads();
    // O: col = dh = db*32+l31, row = q = w*32 + (reg&3)+8*(reg>>2)+4*hi
#pragma unroll
    for (int g = 0; g < 4; g++) {
#pragma unroll
        for (int r2 = 0; r2 < 4; r2++) {
            int qloc = w * 32 + 4 * hi + r2 + 8 * g;
            float linv = 1.0f / Lw[qloc];
#pragma unroll
            for (int db = 0; db < 2; db++) {
                out[(size_t)(b * kS + q0 + qloc) * kD + h * kDH + db * 32 + l31] = oacc[db][4 * g + r2] * linv;
            }
        }
    }
}

extern "C" void kernel_launch(void* const* d_in, const int* in_sizes, int n_in,
                              void* d_out, int out_size, void* d_ws, size_t ws_size,
                              hipStream_t stream) {
    const float* x  = (const float*)d_in[0];
    const float* Wq = (const float*)d_in[1];
    const float* bq = (const float*)d_in[2];
    const float* Wk = (const float*)d_in[3];
    const float* bk = (const float*)d_in[4];
    const float* Wv = (const float*)d_in[5];
    const float* bv = (const float*)d_in[6];
    float* out = (float*)d_out;

    u16* ws = (u16*)d_ws;
    u16* xb = ws;                   // 8192*768
    u16* wt = xb + 6291456;         // 3*768*768 concat [2304][768]
    u16* qb = wt + 1769472;         // scaled Q bf16
    u16* kb = qb + 6291456;
    u16* vt = kb + 6291456;         // V^T per head (b,h,dh,s), s sigma-permuted (bits 2<->3)

    cvt<<<dim3(7872), dim3(256), 0, stream>>>(x, xb, Wq, Wk, Wv, wt);
    proj<<<dim3(1152), dim3(256), 0, stream>>>(xb, wt, bq, bk, bv, qb, kb, vt);
    attn<<<dim3(768), dim3(256), 0, stream>>>(qb, kb, vt, out);
}